// Round 9
// baseline (325.128 us; speedup 1.0000x reference)
//
#include <hip/hip_runtime.h>
#include <math.h>

typedef __attribute__((ext_vector_type(8))) short short8;
typedef __attribute__((ext_vector_type(4))) float f32x4;
typedef __attribute__((ext_vector_type(4))) unsigned int uint4v;

#define HIDDEN 1024
#define QOUT 2048
#define KVOUT 1024
#define HD 128
#define TSEQ 2048

union U8 { uint4v u; short8 s; };

__device__ __forceinline__ float bf2f(unsigned short h) {
    union { unsigned int u; float f; } x; x.u = ((unsigned int)h) << 16; return x.f;
}
__device__ __forceinline__ unsigned short f2bf(float f) {
    union { float f; unsigned int u; } x; x.f = f;
    unsigned int r = (x.u + 0x7fffu + ((x.u >> 16) & 1u)) >> 16;
    return (unsigned short)r;
}
__device__ __forceinline__ unsigned int pk2bf(float lo, float hi) {
    return (unsigned int)f2bf(lo) | ((unsigned int)f2bf(hi) << 16);
}

// async global->LDS, 16B per lane; dest = wave-uniform base + lane*16
__device__ __forceinline__ void glds16(const unsigned short* g, unsigned short* l) {
    __builtin_amdgcn_global_load_lds(
        (const __attribute__((address_space(1))) unsigned int*)g,
        (__attribute__((address_space(3))) unsigned int*)l, 16, 0, 0);
}

// ---------------- prep: cast x->bf16  +  4 weight transposes (fp32 KxN -> bf16 NxK) ---------
__global__ __launch_bounds__(256) void prep(const float* __restrict__ x,
                                            const float* __restrict__ Wq,
                                            const float* __restrict__ Wk,
                                            const float* __restrict__ Wv,
                                            const float* __restrict__ Wo,
                                            unsigned short* __restrict__ xb,
                                            unsigned short* __restrict__ Wt,
                                            unsigned short* __restrict__ Wot) {
    int bid = blockIdx.x;
    int tid = threadIdx.x;
    if (bid < 4096) {  // cast: 1M float4
        int i = bid * 256 + tid;
        float4 v = *(const float4*)(x + (size_t)i * 4);
        unsigned short o[4] = {f2bf(v.x), f2bf(v.y), f2bf(v.z), f2bf(v.w)};
        *(unsigned long long*)(xb + (size_t)i * 4) = *(unsigned long long*)o;
        return;
    }
    bid -= 4096;
    const float* W; unsigned short* D; int K, N;
    if (bid < 512)       { W = Wq; D = Wt;                          K = 1024; N = 2048; }
    else if (bid < 768)  { bid -= 512;  W = Wk; D = Wt + (size_t)2048 * 1024; K = 1024; N = 1024; }
    else if (bid < 1024) { bid -= 768;  W = Wv; D = Wt + (size_t)3072 * 1024; K = 1024; N = 1024; }
    else                 { bid -= 1024; W = Wo; D = Wot;                      K = 2048; N = 1024; }
    __shared__ __attribute__((aligned(16))) unsigned short Ls[64 * 72];
    int ntiles = N >> 6;
    int kt = bid / ntiles, nt = bid - kt * ntiles;
    int k0 = kt * 64, n0 = nt * 64;
    for (int t = 0; t < 4; t++) {
        int idx = tid + t * 256;
        int r = idx >> 4, seg = idx & 15;
        float4 v = *(const float4*)(W + (size_t)(k0 + r) * N + n0 + seg * 4);
        int c = seg * 4;
        Ls[(c + 0) * 72 + r] = f2bf(v.x);
        Ls[(c + 1) * 72 + r] = f2bf(v.y);
        Ls[(c + 2) * 72 + r] = f2bf(v.z);
        Ls[(c + 3) * 72 + r] = f2bf(v.w);
    }
    __syncthreads();
    for (int t = 0; t < 2; t++) {
        int idx = tid + t * 256;
        int rr = idx >> 3, seg = idx & 7;
        uint4v v = *(const uint4v*)(Ls + rr * 72 + seg * 8);
        *(uint4v*)(D + (size_t)(n0 + rr) * K + k0 + seg * 8) = v;
    }
}

// ---------------- GEMM: C[M,N] = A[M,K](bf16) @ Bt[N,K]^T(bf16) ----------------
// Single-barrier double-buffered glds16 staging.
template <int OUT_BF16, int BN>
__global__ __launch_bounds__(256) void gemm_bt(const unsigned short* __restrict__ A,
                                               const unsigned short* __restrict__ Bt,
                                               void* __restrict__ Cout,
                                               int M, int N, int K) {
    constexpr int MT = (BN == 128) ? 4 : 2;
    __shared__ __attribute__((aligned(16))) unsigned short As[2][128 * 32];
    __shared__ __attribute__((aligned(16))) unsigned short Bs[2][BN * 32];
    const int tid = threadIdx.x;
    const int lane = tid & 63;
    const int warp = tid >> 6;
    const int ln = lane & 15;
    const int quad = lane >> 4;
    const int wm = (BN == 128) ? (warp >> 1) : warp;
    const int wn = (BN == 128) ? (warp & 1) : 0;
    const int m0 = blockIdx.y * 128;
    const int n0 = blockIdx.x * BN;

    const int srow = lane >> 2;
    const int schunk = (lane & 3) ^ (srow & 3);
    const unsigned short* Ag = A + (size_t)(m0 + warp * 16 + srow) * K + schunk * 8;
    const unsigned short* Bg = Bt + (size_t)(n0 + warp * 16 + srow) * K + schunk * 8;

    f32x4 acc[MT][4];
#pragma unroll
    for (int i = 0; i < MT; i++)
#pragma unroll
        for (int j = 0; j < 4; j++) acc[i][j] = (f32x4){0.f, 0.f, 0.f, 0.f};

    auto stage = [&](int k0, int bi) {
        glds16(Ag + k0, As[bi] + warp * 16 * 32);
        glds16(Ag + (size_t)64 * K + k0, As[bi] + warp * 16 * 32 + 64 * 32);
        glds16(Bg + k0, Bs[bi] + warp * 16 * 32);
        if (BN == 128) glds16(Bg + (size_t)64 * K + k0, Bs[bi] + warp * 16 * 32 + 64 * 32);
    };

    const int rq = quad ^ (ln & 3);   // swizzled read chunk
    const int KI = K >> 5;
    stage(0, 0);
    for (int it = 0; it < KI; it++) {
        __syncthreads();            // drains my glds for buf it&1
        if (it + 1 < KI) stage((it + 1) << 5, (it + 1) & 1);
        const unsigned short* Ab = As[it & 1];
        const unsigned short* Bb = Bs[it & 1];
        short8 af[MT], bf[4];
#pragma unroll
        for (int mt = 0; mt < MT; mt++)
            af[mt] = *(const short8*)(Ab + (wm * (MT * 16) + mt * 16 + ln) * 32 + rq * 8);
#pragma unroll
        for (int nt = 0; nt < 4; nt++)
            bf[nt] = *(const short8*)(Bb + (wn * 64 + nt * 16 + ln) * 32 + rq * 8);
#pragma unroll
        for (int mt = 0; mt < MT; mt++)
#pragma unroll
            for (int nt = 0; nt < 4; nt++)
                acc[mt][nt] = __builtin_amdgcn_mfma_f32_16x16x32_bf16(bf[nt], af[mt], acc[mt][nt], 0, 0, 0);
    }
#pragma unroll
    for (int mt = 0; mt < MT; mt++) {
        int row = m0 + wm * (MT * 16) + mt * 16 + ln;
#pragma unroll
        for (int nt = 0; nt < 4; nt++) {
            int colb = n0 + wn * 64 + nt * 16 + quad * 4;
            if (OUT_BF16) {
                unsigned long long pk =
                    (unsigned long long)pk2bf(acc[mt][nt][0], acc[mt][nt][1]) |
                    ((unsigned long long)pk2bf(acc[mt][nt][2], acc[mt][nt][3]) << 32);
                *(unsigned long long*)((unsigned short*)Cout + (size_t)row * N + colb) = pk;
            } else {
                *(f32x4*)((float*)Cout + (size_t)row * N + colb) = acc[mt][nt];
            }
        }
    }
}

// ---------------- fused norm_rope (blocks < 24576) + v_transpose (rest) ----------------
__global__ __launch_bounds__(256) void nrvt(const unsigned short* __restrict__ QKV,
                                            const float* __restrict__ qw,
                                            const float* __restrict__ kw,
                                            unsigned short* __restrict__ Q,
                                            unsigned short* __restrict__ Kb,
                                            unsigned short* __restrict__ Vt) {
    if (blockIdx.x < 24576) {
        int warp = threadIdx.x >> 6;
        int lane = threadIdx.x & 63;
        int gid = blockIdx.x * 4 + warp;
        int tok = gid / 24;
        int slot = gid - tok * 24;
        int b = tok >> 11, t = tok & 2047;
        const float* w;
        unsigned short* dst;
        int col0;
        if (slot < 16) {
            col0 = slot * HD;
            dst = Q + ((size_t)(b * 16 + slot) * TSEQ + t) * HD;
            w = qw;
        } else {
            int hk = slot - 16;
            col0 = QOUT + hk * HD;
            dst = Kb + ((size_t)(b * 8 + hk) * TSEQ + t) * HD;
            w = kw;
        }
        const unsigned short* row = QKV + (size_t)tok * 4096 + col0;
        float e0 = bf2f(row[lane]), e1 = bf2f(row[lane + 64]);
        float ss = e0 * e0 + e1 * e1;
        for (int off = 1; off < 64; off <<= 1) ss += __shfl_xor(ss, off);
        float rr = rsqrtf(ss * (1.0f / 128.0f) + 1e-6f);
        float n0 = e0 * rr * w[lane];
        float n1 = e1 * rr * w[lane + 64];
        float invf = __builtin_exp2f(-(float)lane * 0.20762050593045951f);
        float ang = (float)t * invf;
        float sf, cf;
        __sincosf(ang, &sf, &cf);
        dst[lane] = f2bf(n0 * cf - n1 * sf);
        dst[lane + 64] = f2bf(n1 * cf + n0 * sf);
        return;
    }
    // v_transpose
    __shared__ __attribute__((aligned(16))) unsigned short Ls[128 * 72];
    int bid = blockIdx.x - 24576;
    int tt = bid & 31, hk = (bid >> 5) & 7, b = bid >> 8;
    int t0 = tt * 64;
    int tid = threadIdx.x;
    const unsigned short* base = QKV + (size_t)(b * 2048 + t0) * 4096 + 3072 + hk * 128;
    for (int i = 0; i < 4; i++) {
        int idx = tid + i * 256;
        int r = idx >> 4, seg = idx & 15;
        uint4v v = *(const uint4v*)(base + (size_t)r * 4096 + seg * 8);
        unsigned short* pv = (unsigned short*)&v;
        int d = seg * 8;
        for (int jj = 0; jj < 8; jj++) Ls[(d + jj) * 72 + r] = pv[jj];
    }
    __syncthreads();
    unsigned short* out = Vt + (size_t)(b * 8 + hk) * 128 * 2048;
    for (int i = 0; i < 4; i++) {
        int idx = tid + i * 256;
        int d = idx >> 3, seg = idx & 7;
        uint4v v = *(const uint4v*)(Ls + d * 72 + seg * 8);
        *(uint4v*)(out + (size_t)d * 2048 + t0 + seg * 8) = v;
    }
}

// ---------------- flash attention v8: one 64-row tile per block, 16 waves/CU ----------------
// grid (32 tiles big-first, 32 b*h), 256 thr (4 waves x 16 rows). LDS exactly 32 KB ->
// 4 blocks/CU. No idle waves (tile t iterates j=0..t; mask only on diagonal). P layout
// transform via quad shuffles (no Ps LDS). Sync single-buffer staging (dbuf regressed).
__global__ __launch_bounds__(256, 4) void attn(const unsigned short* __restrict__ Q,
                                               const unsigned short* __restrict__ Kg,
                                               const unsigned short* __restrict__ Vt,
                                               unsigned short* __restrict__ Og) {
    __shared__ __attribute__((aligned(16))) unsigned short Ks[64 * 128];  // swizzled (kv, d)
    __shared__ __attribute__((aligned(16))) unsigned short Vs[128 * 64];  // swizzled (d, kv)
    const int t = 31 - (int)blockIdx.x;   // big tiles dispatched first
    const int bh = blockIdx.y;
    const int b = bh >> 4, h = bh & 15, hk = h >> 1;
    const int tid = threadIdx.x;
    const int warp = tid >> 6, lane = tid & 63, ln = lane & 15, quad = lane >> 4;
    const int row0 = t * 64 + warp * 16;

    const unsigned short* Kbase = Kg + (size_t)(b * 8 + hk) * TSEQ * HD;
    const unsigned short* Vbase = Vt + (size_t)(b * 8 + hk) * HD * TSEQ;
    const unsigned short* Qh = Q + (size_t)(b * 16 + h) * TSEQ * HD;

    short8 qf[4];
#pragma unroll
    for (int kt = 0; kt < 4; kt++)
        qf[kt] = *(const short8*)(Qh + (size_t)(row0 + ln) * HD + kt * 32 + quad * 8);

    f32x4 o[8];
#pragma unroll
    for (int ot = 0; ot < 8; ot++) o[ot] = (f32x4){0.f, 0.f, 0.f, 0.f};
    float m_ = -1e30f, l_ = 0.f;

    const int kr = lane >> 4;
    const int kc = lane & 15;
    const int vr = lane >> 3;
    const int vc = lane & 7;
    // P-shuffle constants (verified v4 layout transform)
    const int baseq = (quad & 1) * 2;
    const int i0 = ln + 16 * baseq;
    const int i1 = ln + 16 * (baseq + 1);
    const bool qlow = quad < 2;

    const float kscale = 0.12750580997495268f;  // (1/sqrt(128)) * log2(e)
    for (int j = 0; j <= t; j++) {
        const int j0 = j * 64;
        __syncthreads();
#pragma unroll
        for (int c = 0; c < 4; c++) {   // K: LDS[r][c] = K[r][c ^ (r&15)]
            int row = warp * 16 + c * 4 + kr;
            glds16(Kbase + (size_t)(j0 + row) * HD + ((kc ^ (row & 15)) * 8),
                   Ks + (warp * 16 + c * 4) * 128);
        }
#pragma unroll
        for (int c = 0; c < 4; c++) {   // V^T: LDS[d][c] = V[d][c ^ (d&7)]
            int d = warp * 32 + c * 8 + vr;
            glds16(Vbase + (size_t)d * TSEQ + j0 + ((vc ^ (d & 7)) * 8),
                   Vs + (warp * 32 + c * 8) * 64);
        }
        __syncthreads();
        // ---- S^T = K x Q: lane holds 16 kv (kb*16+quad*4+r) for q-row row0+ln ----
        f32x4 s[4];
#pragma unroll
        for (int kb = 0; kb < 4; kb++) s[kb] = (f32x4){0.f, 0.f, 0.f, 0.f};
#pragma unroll
        for (int kt = 0; kt < 4; kt++) {
            short8 kf[4];
#pragma unroll
            for (int kb = 0; kb < 4; kb++)
                kf[kb] = *(const short8*)(Ks + (kb * 16 + ln) * 128 + (((kt * 4 + quad) ^ ln) * 8));
#pragma unroll
            for (int kb = 0; kb < 4; kb++)
                s[kb] = __builtin_amdgcn_mfma_f32_16x16x32_bf16(kf[kb], qf[kt], s[kb], 0, 0, 0);
        }
        // ---- softmax (log2 domain) ----
        float mx = -1e30f;
        if (j == t) {   // diagonal tile: causal mask
            const int qloc = warp * 16 + ln;
#pragma unroll
            for (int kb = 0; kb < 4; kb++)
#pragma unroll
                for (int r = 0; r < 4; r++) {
                    int kvloc = kb * 16 + quad * 4 + r;
                    float v = s[kb][r] * kscale;
                    v = (kvloc > qloc) ? -1e30f : v;
                    s[kb][r] = v;
                    mx = fmaxf(mx, v);
                }
        } else {
#pragma unroll
            for (int kb = 0; kb < 4; kb++)
#pragma unroll
                for (int r = 0; r < 4; r++) {
                    float v = s[kb][r] * kscale;
                    s[kb][r] = v;
                    mx = fmaxf(mx, v);
                }
        }
        mx = fmaxf(mx, __shfl_xor(mx, 16));
        mx = fmaxf(mx, __shfl_xor(mx, 32));
        float mn = fmaxf(m_, mx);
        float al = __builtin_exp2f(m_ - mn);
        float sum = 0.f;
#pragma unroll
        for (int kb = 0; kb < 4; kb++)
#pragma unroll
            for (int r = 0; r < 4; r++) {
                float pv = __builtin_exp2f(s[kb][r] - mn);
                s[kb][r] = pv;
                sum += pv;
            }
        sum += __shfl_xor(sum, 16);
        sum += __shfl_xor(sum, 32);
        m_ = mn;
        l_ = l_ * al + sum;
        // ---- pack P pairs and shuffle into B-operand layout (pf0: kv 0..31, pf1: 32..63) ----
        unsigned int P2[4][2];
#pragma unroll
        for (int kb = 0; kb < 4; kb++) {
            P2[kb][0] = pk2bf(s[kb][0], s[kb][1]);
            P2[kb][1] = pk2bf(s[kb][2], s[kb][3]);
        }
        U8 pf0, pf1;
        {
            unsigned a, bb;
            a = __shfl(P2[0][0], i0); bb = __shfl(P2[1][0], i0); pf0.u[0] = qlow ? a : bb;
            a = __shfl(P2[0][1], i0); bb = __shfl(P2[1][1], i0); pf0.u[1] = qlow ? a : bb;
            a = __shfl(P2[0][0], i1); bb = __shfl(P2[1][0], i1); pf0.u[2] = qlow ? a : bb;
            a = __shfl(P2[0][1], i1); bb = __shfl(P2[1][1], i1); pf0.u[3] = qlow ? a : bb;
            a = __shfl(P2[2][0], i0); bb = __shfl(P2[3][0], i0); pf1.u[0] = qlow ? a : bb;
            a = __shfl(P2[2][1], i0); bb = __shfl(P2[3][1], i0); pf1.u[1] = qlow ? a : bb;
            a = __shfl(P2[2][0], i1); bb = __shfl(P2[3][0], i1); pf1.u[2] = qlow ? a : bb;
            a = __shfl(P2[2][1], i1); bb = __shfl(P2[3][1], i1); pf1.u[3] = qlow ? a : bb;
        }
        // ---- rescale O (per-lane alpha, q = ln) ----
        if (__any(al != 1.0f))
#pragma unroll
            for (int ot = 0; ot < 8; ot++)
#pragma unroll
                for (int r = 0; r < 4; r++) o[ot][r] *= al;
        // ---- PV, operand-swapped (O: col=q=ln, rows=d) ----
#pragma unroll
        for (int ot = 0; ot < 8; ot++) {
            short8 vf0 = *(const short8*)(Vs + (ot * 16 + ln) * 64 + ((quad ^ (ln & 7)) * 8));
            short8 vf1 = *(const short8*)(Vs + (ot * 16 + ln) * 64 + (((4 + quad) ^ (ln & 7)) * 8));
            o[ot] = __builtin_amdgcn_mfma_f32_16x16x32_bf16(vf0, pf0.s, o[ot], 0, 0, 0);
            o[ot] = __builtin_amdgcn_mfma_f32_16x16x32_bf16(vf1, pf1.s, o[ot], 0, 0, 0);
        }
    }
    // epilogue: lane has q = row0+ln; regs are 4 consecutive d -> 8B stores
    float inv = 1.0f / l_;
    size_t rowoff = ((size_t)(b * TSEQ + row0 + ln)) * QOUT + h * 128 + quad * 4;
#pragma unroll
    for (int ot = 0; ot < 8; ot++) {
        unsigned long long pk =
            (unsigned long long)pk2bf(o[ot][0] * inv, o[ot][1] * inv) |
            ((unsigned long long)pk2bf(o[ot][2] * inv, o[ot][3] * inv) << 32);
        *(unsigned long long*)(Og + rowoff + ot * 16) = pk;
    }
}

extern "C" void kernel_launch(void* const* d_in, const int* in_sizes, int n_in,
                              void* d_out, int out_size, void* d_ws, size_t ws_size,
                              hipStream_t stream) {
    (void)in_sizes; (void)n_in; (void)out_size;
    const float* x  = (const float*)d_in[0];
    const float* Wq = (const float*)d_in[1];
    const float* Wk = (const float*)d_in[2];
    const float* Wv = (const float*)d_in[3];
    const float* Wo = (const float*)d_in[4];
    const float* qw = (const float*)d_in[5];
    const float* kw = (const float*)d_in[6];

    char* ws = (char*)d_ws;
    const size_t MB = 1024 * 1024;
    unsigned short* Wt   = (unsigned short*)(ws);            // 8 MB
    unsigned short* Wot  = (unsigned short*)(ws + 8 * MB);   // 4 MB
    unsigned short* QKVb = (unsigned short*)(ws + 12 * MB);  // 32 MB (bf16)
    unsigned short* xb   = (unsigned short*)(ws + 44 * MB);  // 8 MB
    unsigned short* Qb   = (unsigned short*)(ws + 52 * MB);  // 16 MB
    unsigned short* Kb   = (unsigned short*)(ws + 68 * MB);  // 8 MB
    unsigned short* Vtb  = (unsigned short*)(ws + 76 * MB);  // 8 MB
    unsigned short* Ob   = (unsigned short*)(ws + 84 * MB);  // 16 MB
    if (ws_size < 100 * MB) return;

    prep<<<dim3(5632), 256, 0, stream>>>(x, Wq, Wk, Wv, Wo, xb, Wt, Wot);
    gemm_bt<1, 128><<<dim3(32, 32), 256, 0, stream>>>(xb, Wt, QKVb, 4096, 4096, 1024);
    nrvt<<<dim3(25088), 256, 0, stream>>>(QKVb, qw, kw, Qb, Kb, Vtb);
    attn<<<dim3(32, 32), 256, 0, stream>>>(Qb, Kb, Vtb, Ob);
    gemm_bt<0, 64><<<dim3(16, 32), 256, 0, stream>>>(Ob, Wot, (float*)d_out, 4096, 1024, 2048);
}